// Round 1
// baseline (306.312 us; speedup 1.0000x reference)
//
#include <hip/hip_runtime.h>
#include <math.h>

#define BB 8
#define CC 512
#define HH 80
#define WW 80
#define HWSZ 6400
#define NN 100
#define HR 40
#define WR 40
#define VV 20   // N_CLASSES_FG
#define VO 21   // BG + 20 FG

// ---------------- K1: build normalized prototypes (1 block, 512 threads) ----
__global__ __launch_bounds__(512) void k_protos(const float* __restrict__ refc,
                                                const int* __restrict__ coord,
                                                const int* __restrict__ cls,
                                                float* __restrict__ protosN) {
    __shared__ float sAcc[VV][CC];   // 40 KB
    __shared__ float sCnt[VV];
    __shared__ float sScale[VV];
    const int c = threadIdx.x;       // 0..511, one channel per thread

    #pragma unroll
    for (int v = 0; v < VV; ++v) sAcc[v][c] = 0.f;

    // gather + segment-sum: each thread owns one channel column
    for (int n = 0; n < NN; ++n) {
        int cm = cls[n];                       // uniform across threads
        int y = coord[2 * n + 1];
        int x = coord[2 * n + 0];
        float val = refc[((size_t)(n * CC + c) * HR + y) * WR + x];
        sAcc[cm][c] += val;
    }
    if (c < VV) {
        int cnt = 0;
        for (int n = 0; n < NN; ++n) cnt += (cls[n] == c) ? 1 : 0;
        sCnt[c] = fmaxf((float)cnt, 1.0f);
    }
    __syncthreads();

    // divide by counts
    #pragma unroll
    for (int v = 0; v < VV; ++v) sAcc[v][c] = sAcc[v][c] / sCnt[v];
    __syncthreads();

    // L2 norm per class: one wave per class (8 waves in block)
    const int wave = threadIdx.x >> 6;
    const int lane = threadIdx.x & 63;
    for (int v = wave; v < VV; v += 8) {
        float ss = 0.f;
        #pragma unroll
        for (int k = lane; k < CC; k += 64) {
            float t = sAcc[v][k];
            ss = fmaf(t, t, ss);
        }
        #pragma unroll
        for (int off = 32; off; off >>= 1) ss += __shfl_xor(ss, off);
        if (lane == 0) sScale[v] = 1.0f / fmaxf(sqrtf(ss), 1e-10f);
    }
    __syncthreads();

    #pragma unroll
    for (int v = 0; v < VV; ++v) protosN[v * CC + c] = sAcc[v][c] * sScale[v];
}

// ---------------- K2: prob_C = norm(code_C) . protosN, + per-pixel sum ------
__global__ __launch_bounds__(256) void k_probC(const float* __restrict__ codeC,
                                               const float* __restrict__ protosN,
                                               float* __restrict__ probC,
                                               float* __restrict__ sums) {
    __shared__ float sP[VV * CC];    // 40 KB
    const int tid = threadIdx.x;
    for (int i = tid; i < VV * CC; i += 256) sP[i] = protosN[i];
    __syncthreads();

    const int b = blockIdx.x / 25;
    const int p = (blockIdx.x % 25) * 256 + tid;
    const float* src = codeC + (size_t)b * CC * HWSZ + p;

    float d[VV];
    #pragma unroll
    for (int v = 0; v < VV; ++v) d[v] = 0.f;
    float ss = 0.f;

    #pragma unroll 8
    for (int c = 0; c < CC; ++c) {
        float x = src[(size_t)c * HWSZ];
        ss = fmaf(x, x, ss);
        #pragma unroll
        for (int v = 0; v < VV; ++v) d[v] = fmaf(x, sP[v * CC + c], d[v]);
    }

    float scale = 1.0f / fmaxf(sqrtf(ss), 1e-10f);
    float sum = 0.f;
    float* dst = probC + (size_t)b * VV * HWSZ + p;
    #pragma unroll
    for (int v = 0; v < VV; ++v) {
        float pv = d[v] * scale;
        dst[(size_t)v * HWSZ] = pv;
        sum += pv;
    }
    sums[b * HWSZ + p] = sum;
}

// ---------------- K3: per-batch argmin + normalized min_vec -----------------
__global__ __launch_bounds__(256) void k_argmin(const float* __restrict__ sums,
                                                const float* __restrict__ codeBG,
                                                float* __restrict__ minvecN) {
    const int b = blockIdx.x;
    const int tid = threadIdx.x;

    float best = INFINITY;
    int bidx = 0x7fffffff;
    for (int p = tid; p < HWSZ; p += 256) {
        float v = sums[b * HWSZ + p];
        if (v < best || (v == best && p < bidx)) { best = v; bidx = p; }
    }
    __shared__ float sV[256];
    __shared__ int   sI[256];
    sV[tid] = best; sI[tid] = bidx;
    __syncthreads();
    for (int off = 128; off; off >>= 1) {
        if (tid < off) {
            float v2 = sV[tid + off]; int i2 = sI[tid + off];
            if (v2 < sV[tid] || (v2 == sV[tid] && i2 < sI[tid])) {
                sV[tid] = v2; sI[tid] = i2;
            }
        }
        __syncthreads();
    }
    const int pix = sI[0];

    // normalize code_BG[b, :, pix]
    __shared__ float sX[CC];
    __shared__ float sR[256];
    float ssp = 0.f;
    for (int c = tid; c < CC; c += 256) {
        float x = codeBG[(size_t)(b * CC + c) * HWSZ + pix];
        sX[c] = x;
        ssp = fmaf(x, x, ssp);
    }
    sR[tid] = ssp;
    __syncthreads();
    for (int off = 128; off; off >>= 1) {
        if (tid < off) sR[tid] += sR[tid + off];
        __syncthreads();
    }
    float scale = 1.0f / fmaxf(sqrtf(sR[0]), 1e-10f);
    for (int c = tid; c < CC; c += 256) minvecN[b * CC + c] = sX[c] * scale;
}

// ---------------- K4: prob_BG + fused softmax + output ----------------------
__global__ __launch_bounds__(256) void k_bg_softmax(const float* __restrict__ codeBG,
                                                    const float* __restrict__ minvecN,
                                                    const float* __restrict__ probC,
                                                    float* __restrict__ out) {
    __shared__ float sM[CC];    // normalized min_vec for this batch (2 KB)
    const int tid = threadIdx.x;
    const int b = blockIdx.x / 25;
    const int p = (blockIdx.x % 25) * 256 + tid;

    for (int c = tid; c < CC; c += 256) sM[c] = minvecN[b * CC + c];
    __syncthreads();

    const float* src = codeBG + (size_t)b * CC * HWSZ + p;
    float ss = 0.f, dbg = 0.f;
    #pragma unroll 8
    for (int c = 0; c < CC; ++c) {
        float x = src[(size_t)c * HWSZ];
        ss  = fmaf(x, x, ss);
        dbg = fmaf(x, sM[c], dbg);
    }
    float pbg = dbg * (1.0f / fmaxf(sqrtf(ss), 1e-10f));

    float pv[VO];
    pv[0] = pbg;
    const float* pc = probC + (size_t)b * VV * HWSZ + p;
    #pragma unroll
    for (int v = 0; v < VV; ++v) pv[v + 1] = pc[(size_t)v * HWSZ];

    float m = pv[0];
    #pragma unroll
    for (int i = 1; i < VO; ++i) m = fmaxf(m, pv[i]);
    float se = 0.f;
    #pragma unroll
    for (int i = 0; i < VO; ++i) { pv[i] = __expf(pv[i] - m); se += pv[i]; }
    float inv = 1.0f / se;

    float* dst = out + (size_t)b * VO * HWSZ + p;
    #pragma unroll
    for (int i = 0; i < VO; ++i) dst[(size_t)i * HWSZ] = pv[i] * inv;
}

extern "C" void kernel_launch(void* const* d_in, const int* in_sizes, int n_in,
                              void* d_out, int out_size, void* d_ws, size_t ws_size,
                              hipStream_t stream) {
    const float* codeC  = (const float*)d_in[0];
    const float* codeBG = (const float*)d_in[1];
    const float* refc   = (const float*)d_in[2];
    // d_in[3] (ref_code_bg) is unused by the reference
    const int* coord = (const int*)d_in[4];
    const int* cls   = (const int*)d_in[5];
    float* out = (float*)d_out;

    char* ws = (char*)d_ws;
    float* protosN = (float*)(ws);                               // 40,960 B
    float* probC   = (float*)(ws + 40960);                       // 4,096,000 B
    float* sums    = (float*)(ws + 40960 + 4096000);             // 204,800 B
    float* minvecN = (float*)(ws + 40960 + 4096000 + 204800);    // 16,384 B

    k_protos<<<dim3(1), dim3(512), 0, stream>>>(refc, coord, cls, protosN);
    k_probC<<<dim3(200), dim3(256), 0, stream>>>(codeC, protosN, probC, sums);
    k_argmin<<<dim3(8), dim3(256), 0, stream>>>(sums, codeBG, minvecN);
    k_bg_softmax<<<dim3(200), dim3(256), 0, stream>>>(codeBG, minvecN, probC, out);
}

// Round 2
// 70.668 us; speedup vs baseline: 4.3345x; 4.3345x over previous
//
#include <hip/hip_runtime.h>
#include <math.h>

#define BB 8
#define CC 512
#define HWSZ 6400
#define NN 100
#define HR 40
#define WR 40
#define VV 20   // N_CLASSES_FG
#define VO 21   // BG + 20 FG

// ---------------- K1: normalized prototypes, transposed [c][v] -------------
// grid = 20 blocks (one per class), 512 threads (one per channel).
// Deterministic: every block scans n=0..99 in order (uniform branch).
__global__ __launch_bounds__(512) void k_protos(const float* __restrict__ refc,
                                                const int* __restrict__ coord,
                                                const int* __restrict__ cls,
                                                float* __restrict__ protosT) {
    const int v = blockIdx.x;        // class
    const int c = threadIdx.x;       // channel

    float acc = 0.f;
    int cnt = 0;
    for (int n = 0; n < NN; ++n) {
        if (cls[n] == v) {           // uniform across block
            int y = coord[2 * n + 1];
            int x = coord[2 * n + 0];
            acc += refc[((size_t)(n * CC + c) * HR + y) * WR + x];
            ++cnt;
        }
    }
    acc /= fmaxf((float)cnt, 1.0f);

    // L2 norm across the 512 channels
    float ss = acc * acc;
    #pragma unroll
    for (int off = 32; off; off >>= 1) ss += __shfl_xor(ss, off);
    __shared__ float sW[8];
    const int wave = c >> 6, lane = c & 63;
    if (lane == 0) sW[wave] = ss;
    __syncthreads();
    float tot = 0.f;
    #pragma unroll
    for (int w = 0; w < 8; ++w) tot += sW[w];
    float scale = 1.0f / fmaxf(sqrtf(tot), 1e-10f);

    protosT[c * VV + v] = acc * scale;   // transposed layout for scalar loads
}

// ---------------- K2: prob_C + per-pixel sum --------------------------------
// grid = 800 (8 b x 100 px-tiles), block = 512 = 8 waves.
// wave w handles channels [w*64, w*64+64) for the tile's 64 pixels.
__global__ __launch_bounds__(512, 6) void k_probC(const float* __restrict__ codeC,
                                                  const float* __restrict__ protosT,
                                                  float* __restrict__ probC,
                                                  float* __restrict__ sums) {
    __shared__ float red[8 * VO * 64];   // [wave][v(21)][px(64)] = 43 KB
    __shared__ float sScale[64];

    const int tid  = threadIdx.x;
    const int wave = tid >> 6, lane = tid & 63;
    const int b    = blockIdx.x / 100;
    const int tile = blockIdx.x % 100;

    const int c0 = __builtin_amdgcn_readfirstlane(wave * 64);  // force SGPR
    const float* src = codeC + ((size_t)(b * CC + c0)) * HWSZ + tile * 64 + lane;
    const float* pt  = protosT + (size_t)c0 * VV;              // uniform → s_load

    float d[VV];
    #pragma unroll
    for (int v = 0; v < VV; ++v) d[v] = 0.f;
    float ss = 0.f;

    #pragma unroll 4
    for (int c = 0; c < 64; ++c) {
        float x = src[(size_t)c * HWSZ];
        ss = fmaf(x, x, ss);
        const float* pr = pt + c * VV;
        #pragma unroll
        for (int v = 0; v < VV; ++v) d[v] = fmaf(x, pr[v], d[v]);
    }

    // cross-wave reduction
    #pragma unroll
    for (int v = 0; v < VV; ++v) red[(wave * VO + v) * 64 + lane] = d[v];
    red[(wave * VO + VV) * 64 + lane] = ss;
    __syncthreads();

    for (int q = tid; q < VO * 64; q += 512) {
        float t = red[q];
        #pragma unroll
        for (int w = 1; w < 8; ++w) t += red[w * VO * 64 + q];
        red[q] = t;
    }
    __syncthreads();

    if (tid < 64) {
        float ssum = red[VV * 64 + tid];
        sScale[tid] = 1.0f / fmaxf(sqrtf(ssum), 1e-10f);
    }
    __syncthreads();

    float* dst = probC + (size_t)b * VV * HWSZ + tile * 64;
    for (int q = tid; q < VV * 64; q += 512) {
        int v = q >> 6, px = q & 63;
        dst[(size_t)v * HWSZ + px] = red[q] * sScale[px];
    }
    if (tid < 64) {
        float tot = 0.f;
        #pragma unroll
        for (int v = 0; v < VV; ++v) tot += red[v * 64 + tid];
        sums[b * HWSZ + tile * 64 + tid] = tot * sScale[tid];
    }
}

// ---------------- K3: per-batch argmin + normalized min_vec -----------------
__global__ __launch_bounds__(256) void k_argmin(const float* __restrict__ sums,
                                                const float* __restrict__ codeBG,
                                                float* __restrict__ minvecN) {
    const int b = blockIdx.x;
    const int tid = threadIdx.x;

    float best = INFINITY;
    int bidx = 0x7fffffff;
    for (int p = tid; p < HWSZ; p += 256) {
        float v = sums[b * HWSZ + p];
        if (v < best || (v == best && p < bidx)) { best = v; bidx = p; }
    }
    __shared__ float sV[256];
    __shared__ int   sI[256];
    sV[tid] = best; sI[tid] = bidx;
    __syncthreads();
    for (int off = 128; off; off >>= 1) {
        if (tid < off) {
            float v2 = sV[tid + off]; int i2 = sI[tid + off];
            if (v2 < sV[tid] || (v2 == sV[tid] && i2 < sI[tid])) {
                sV[tid] = v2; sI[tid] = i2;
            }
        }
        __syncthreads();
    }
    const int pix = sI[0];

    __shared__ float sX[CC];
    __shared__ float sR[256];
    float ssp = 0.f;
    for (int c = tid; c < CC; c += 256) {
        float x = codeBG[(size_t)(b * CC + c) * HWSZ + pix];
        sX[c] = x;
        ssp = fmaf(x, x, ssp);
    }
    sR[tid] = ssp;
    __syncthreads();
    for (int off = 128; off; off >>= 1) {
        if (tid < off) sR[tid] += sR[tid + off];
        __syncthreads();
    }
    float scale = 1.0f / fmaxf(sqrtf(sR[0]), 1e-10f);
    for (int c = tid; c < CC; c += 256) minvecN[b * CC + c] = sX[c] * scale;
}

// ---------------- K4: prob_BG + fused softmax + output ----------------------
// Same 8-wave channel-split structure as K2.
__global__ __launch_bounds__(512, 6) void k_bg_softmax(const float* __restrict__ codeBG,
                                                       const float* __restrict__ minvecN,
                                                       const float* __restrict__ probC,
                                                       float* __restrict__ out) {
    __shared__ float red2[8 * 2 * 64];   // [wave][{ss,dbg}][px] = 4 KB

    const int tid  = threadIdx.x;
    const int wave = tid >> 6, lane = tid & 63;
    const int b    = blockIdx.x / 100;
    const int tile = blockIdx.x % 100;

    const int c0 = __builtin_amdgcn_readfirstlane(wave * 64);
    const float* src = codeBG + ((size_t)(b * CC + c0)) * HWSZ + tile * 64 + lane;
    const float* mv  = minvecN + b * CC + c0;   // uniform → s_load

    float ss = 0.f, dg = 0.f;
    #pragma unroll 4
    for (int c = 0; c < 64; ++c) {
        float x = src[(size_t)c * HWSZ];
        ss = fmaf(x, x, ss);
        dg = fmaf(x, mv[c], dg);
    }
    red2[(wave * 2 + 0) * 64 + lane] = ss;
    red2[(wave * 2 + 1) * 64 + lane] = dg;
    __syncthreads();

    if (tid < 128) {
        int kind = tid >> 6, px = tid & 63;
        float t = red2[kind * 64 + px];
        #pragma unroll
        for (int w = 1; w < 8; ++w) t += red2[(w * 2 + kind) * 64 + px];
        red2[kind * 64 + px] = t;
    }
    __syncthreads();

    if (tid < 64) {
        const int px = tid;
        float pbg = red2[64 + px] * (1.0f / fmaxf(sqrtf(red2[px]), 1e-10f));

        float pv[VO];
        pv[0] = pbg;
        const float* pc = probC + (size_t)b * VV * HWSZ + tile * 64 + px;
        #pragma unroll
        for (int v = 0; v < VV; ++v) pv[v + 1] = pc[(size_t)v * HWSZ];

        float m = pv[0];
        #pragma unroll
        for (int i = 1; i < VO; ++i) m = fmaxf(m, pv[i]);
        float se = 0.f;
        #pragma unroll
        for (int i = 0; i < VO; ++i) { pv[i] = __expf(pv[i] - m); se += pv[i]; }
        float inv = 1.0f / se;

        float* dst = out + (size_t)b * VO * HWSZ + tile * 64 + px;
        #pragma unroll
        for (int i = 0; i < VO; ++i) dst[(size_t)i * HWSZ] = pv[i] * inv;
    }
}

extern "C" void kernel_launch(void* const* d_in, const int* in_sizes, int n_in,
                              void* d_out, int out_size, void* d_ws, size_t ws_size,
                              hipStream_t stream) {
    const float* codeC  = (const float*)d_in[0];
    const float* codeBG = (const float*)d_in[1];
    const float* refc   = (const float*)d_in[2];
    // d_in[3] (ref_code_bg) unused by the reference
    const int* coord = (const int*)d_in[4];
    const int* cls   = (const int*)d_in[5];
    float* out = (float*)d_out;

    char* ws = (char*)d_ws;
    float* protosT = (float*)(ws);                               // 40,960 B  [c][v]
    float* probC   = (float*)(ws + 40960);                       // 4,096,000 B
    float* sums    = (float*)(ws + 40960 + 4096000);             // 204,800 B
    float* minvecN = (float*)(ws + 40960 + 4096000 + 204800);    // 16,384 B

    k_protos<<<dim3(VV), dim3(512), 0, stream>>>(refc, coord, cls, protosT);
    k_probC<<<dim3(800), dim3(512), 0, stream>>>(codeC, protosT, probC, sums);
    k_argmin<<<dim3(BB), dim3(256), 0, stream>>>(sums, codeBG, minvecN);
    k_bg_softmax<<<dim3(800), dim3(512), 0, stream>>>(codeBG, minvecN, probC, out);
}